// Round 5
// baseline (417.116 us; speedup 1.0000x reference)
//
#include <hip/hip_runtime.h>
#include <hip/hip_bf16.h>

// EdgeGNN: 3x EdgeConv(mean) + final linear.
// Algebra: h'_i = relu( [h_i | mean_j h_j] @ [Wtop - Wbot; Wbot] + b ), 0 if deg==0.
// R5: GEMM rewritten barrier-free + LDS-free: per-lane MFMA fragments loaded directly
// from global (A rows from Ucat/Hbar, B rows from prepacked [n][k] weights in L2),
// triple-slot register prefetch, fully unrolled K loop. No __syncthreads in GEMM at all.

typedef short short8 __attribute__((ext_vector_type(8)));
typedef float float4v __attribute__((ext_vector_type(4)));

static __device__ __forceinline__ float bf2f(unsigned short u) {
    union { unsigned int i; float f; } c; c.i = ((unsigned int)u) << 16; return c.f;
}
static __device__ __forceinline__ unsigned short f2bf(float f) {
    union { float f; unsigned int i; } c; c.f = f;
    unsigned int u = c.i;
    return (unsigned short)((u + 0x7FFFu + ((u >> 16) & 1u)) >> 16);  // RNE
}

// ---------------- fused setup: deg count + weight prep + x->bf16 ----------------
// blocks [0,EB): count deg.  [EB,EB+192): layer W -> Wc[l] as [n=256][k=512]
//   Wc[n][k] = bf16(W[k][n] - W[k+256][n]) (k<256);  Wc[n][256+k] = bf16(W[k+256][n])
// [EB+192,EB+448): Wf -> Wft [256][1024].  [EB+448,...): x fp32->bf16 into Ucat col 0.
__global__ __launch_bounds__(256)
void setup_kernel(const int* __restrict__ dst, int E, int* __restrict__ deg,
                  const float* __restrict__ W0, const float* __restrict__ W1,
                  const float* __restrict__ W2, const float* __restrict__ Wf,
                  const float* __restrict__ x,
                  unsigned short* __restrict__ Wc0, unsigned short* __restrict__ Wc1,
                  unsigned short* __restrict__ Wc2, unsigned short* __restrict__ Wft,
                  unsigned short* __restrict__ Ucat, int N, int EB) {
    __shared__ float ta[32][33];
    __shared__ float tb[32][33];
    int bb = blockIdx.x;
    int t = threadIdx.x;
    if (bb < EB) {
        int idx = bb * 256 + t;
        if (idx < E) atomicAdd(&deg[dst[idx]], 1);
        return;
    }
    int bb2 = bb - EB;
    int r0 = t >> 5, c = t & 31;
    if (bb2 < 192) {
        const float* W = (bb2 < 64) ? W0 : (bb2 < 128) ? W1 : W2;
        unsigned short* Wc = (bb2 < 64) ? Wc0 : (bb2 < 128) ? Wc1 : Wc2;
        int t64 = bb2 & 63;
        int k0 = (t64 >> 3) * 32, n0 = (t64 & 7) * 32;
#pragma unroll
        for (int it = 0; it < 4; ++it) {
            int r = r0 + it * 8;
            float a = W[(k0 + r) * 256 + n0 + c];
            float bv = W[(k0 + r + 256) * 256 + n0 + c];
            ta[r][c] = a - bv;
            tb[r][c] = bv;
        }
        __syncthreads();
#pragma unroll
        for (int it = 0; it < 4; ++it) {
            int r = r0 + it * 8;  // row in n-space
            Wc[(n0 + r) * 512 + k0 + c] = f2bf(ta[c][r]);
            Wc[(n0 + r) * 512 + 256 + k0 + c] = f2bf(tb[c][r]);
        }
    } else if (bb2 < 448) {
        int t256 = bb2 - 192;
        int k0 = (t256 >> 3) * 32, n0 = (t256 & 7) * 32;
#pragma unroll
        for (int it = 0; it < 4; ++it) {
            int r = r0 + it * 8;
            ta[r][c] = Wf[(k0 + r) * 256 + n0 + c];
        }
        __syncthreads();
#pragma unroll
        for (int it = 0; it < 4; ++it) {
            int r = r0 + it * 8;
            Wft[(n0 + r) * 1024 + k0 + c] = f2bf(ta[c][r]);
        }
    } else {
        long base = (long)(bb2 - 448) * 2048 + t * 8;
        if (base < (long)N * 256) {
            int i = (int)(base >> 8), cc = (int)(base & 255);
            const float4* xp = (const float4*)(x + base);
            float4 v0 = xp[0], v1 = xp[1];
            ushort4 w0, w1;
            w0.x = f2bf(v0.x); w0.y = f2bf(v0.y); w0.z = f2bf(v0.z); w0.w = f2bf(v0.w);
            w1.x = f2bf(v1.x); w1.y = f2bf(v1.y); w1.z = f2bf(v1.z); w1.w = f2bf(v1.w);
            unsigned short* up = Ucat + (long)i * 1024 + cc;
            *(ushort4*)up = w0;
            *(ushort4*)(up + 4) = w1;
        }
    }
}

// ---------------- CSR scan + bucket fill ----------------
__global__ __launch_bounds__(1024) void scan_kernel(const int* __restrict__ deg,
                                                    int* __restrict__ offs,
                                                    int* __restrict__ cursor, int N) {
    __shared__ int sh[1024];
    int t = threadIdx.x;
    int CH = (N + 1023) >> 10;
    int beg = t * CH, end = beg + CH; if (end > N) end = N; if (beg > N) beg = N;
    int s = 0;
    for (int i = beg; i < end; ++i) s += deg[i];
    sh[t] = s;
    __syncthreads();
    for (int off = 1; off < 1024; off <<= 1) {
        int v = 0;
        if (t >= off) v = sh[t - off];
        __syncthreads();
        if (t >= off) sh[t] += v;
        __syncthreads();
    }
    int run = (t > 0) ? sh[t - 1] : 0;
    for (int i = beg; i < end; ++i) {
        offs[i] = run; cursor[i] = run; run += deg[i];
    }
    if (t == 1023) offs[N] = sh[1023];
}

__global__ void fill_kernel(const int* __restrict__ src, const int* __restrict__ dst, int E,
                            int* __restrict__ cursor, int* __restrict__ esrc) {
    int idx = blockIdx.x * 256 + threadIdx.x;
    if (idx < E) {
        int p = atomicAdd(&cursor[dst[idx]], 1);
        esrc[p] = src[idx];
    }
}

// ---------------- gather-mean: Hbar[i] = mean_j H[j] (bf16), one wave per node ----------------
__global__ __launch_bounds__(256)
void agg_kernel(const unsigned short* __restrict__ H, const int* __restrict__ offs,
                const int* __restrict__ esrc, unsigned short* __restrict__ Hbar, int N) {
    int wave = threadIdx.x >> 6, lane = threadIdx.x & 63;
    int i = blockIdx.x * 4 + wave;
    if (i >= N) return;
    int c = lane * 4;
    float a0 = 0.f, a1 = 0.f, a2 = 0.f, a3 = 0.f;
    int e0 = offs[i], e1 = offs[i + 1];
    int e = e0;
    for (; e + 4 <= e1; e += 4) {
        int s0 = esrc[e], s1 = esrc[e + 1], s2 = esrc[e + 2], s3 = esrc[e + 3];
        ushort4 r0 = *(const ushort4*)(H + (long)s0 * 1024 + c);
        ushort4 r1 = *(const ushort4*)(H + (long)s1 * 1024 + c);
        ushort4 r2 = *(const ushort4*)(H + (long)s2 * 1024 + c);
        ushort4 r3 = *(const ushort4*)(H + (long)s3 * 1024 + c);
        a0 += (bf2f(r0.x) + bf2f(r1.x)) + (bf2f(r2.x) + bf2f(r3.x));
        a1 += (bf2f(r0.y) + bf2f(r1.y)) + (bf2f(r2.y) + bf2f(r3.y));
        a2 += (bf2f(r0.z) + bf2f(r1.z)) + (bf2f(r2.z) + bf2f(r3.z));
        a3 += (bf2f(r0.w) + bf2f(r1.w)) + (bf2f(r2.w) + bf2f(r3.w));
    }
    for (; e < e1; ++e) {
        int s0 = esrc[e];
        ushort4 r0 = *(const ushort4*)(H + (long)s0 * 1024 + c);
        a0 += bf2f(r0.x); a1 += bf2f(r0.y); a2 += bf2f(r0.z); a3 += bf2f(r0.w);
    }
    int d = e1 - e0;
    float inv = (d > 0) ? 1.0f / (float)d : 0.0f;
    ushort4 w;
    w.x = f2bf(a0 * inv); w.y = f2bf(a1 * inv); w.z = f2bf(a2 * inv); w.w = f2bf(a3 * inv);
    *(ushort4*)(Hbar + (long)i * 256 + c) = w;
}

// ---------------- barrier-free LDS-free MFMA GEMM ----------------
// Tile 64x64, 4 waves (2x2), wave tile 32x32 (2x2 MFMA 16x16x32).
// A (MODE 0): k<256 from A1 (stride 1024, Ucat window), k>=256 from A2 (stride 256, Hbar).
// A (MODE 1): A1 stride 1024, K=1024.  B: [n][K] row-major (Wc / Wft) — L2-resident.
// Per k-step each lane loads its fragments straight from global; triple-slot rotation
// gives depth-2 prefetch; NO __syncthreads, NO LDS.
template <int MODE, int K>
__global__ __launch_bounds__(256)
void gemm_kernel(const unsigned short* __restrict__ A1,
                 const unsigned short* __restrict__ A2,
                 const unsigned short* __restrict__ Bt,
                 const float* __restrict__ bias,
                 const int* __restrict__ deg,
                 unsigned short* __restrict__ outB,
                 float* __restrict__ outF,
                 int M) {
    constexpr int NS = K / 32;
    int t = threadIdx.x;
    int bm = blockIdx.x, bn = blockIdx.y;
    int lane = t & 63, wave = t >> 6;
    int wm = wave >> 1, wn = wave & 1;
    int lr = lane & 15, q = lane >> 4;

    float4v acc[2][2];
#pragma unroll
    for (int i = 0; i < 2; i++)
#pragma unroll
        for (int j = 0; j < 2; j++) { float4v z = {0.f, 0.f, 0.f, 0.f}; acc[i][j] = z; }

    // per-lane fragment base pointers
    const unsigned short* a1p[2];
    const unsigned short* a2p[2];
    const unsigned short* bp[2];
#pragma unroll
    for (int mi = 0; mi < 2; ++mi) {
        int row = bm * 64 + wm * 32 + mi * 16 + lr;
        if (row >= M) row = M - 1;  // clamp: duplicate row, stores masked below
        a1p[mi] = A1 + (long)row * 1024 + q * 8;
        a2p[mi] = (MODE == 0) ? (A2 + (long)row * 256 + q * 8) : nullptr;
    }
#pragma unroll
    for (int ni = 0; ni < 2; ++ni) {
        int n = bn * 64 + wn * 32 + ni * 16 + lr;
        bp[ni] = Bt + (long)n * K + q * 8;
    }

    auto loadA = [&](int mi, int k) -> short8 {
        if (MODE == 1 || k < 256) return *(const short8*)(a1p[mi] + k);
        return *(const short8*)(a2p[mi] + (k - 256));
    };

    // triple-slot register pipeline: slot s holds k-step ks with ks % 3 == s
    short8 ar[3][2], br[3][2];
#pragma unroll
    for (int mi = 0; mi < 2; ++mi) { ar[0][mi] = loadA(mi, 0); ar[1][mi] = loadA(mi, 32); }
#pragma unroll
    for (int ni = 0; ni < 2; ++ni) { br[0][ni] = *(const short8*)(bp[ni]); br[1][ni] = *(const short8*)(bp[ni] + 32); }

#pragma unroll
    for (int ks = 0; ks < NS; ++ks) {
        int cur = ks % 3;
        int pre = (ks + 2) % 3;
        if (ks + 2 < NS) {
            int k = (ks + 2) * 32;
#pragma unroll
            for (int mi = 0; mi < 2; ++mi) ar[pre][mi] = loadA(mi, k);
#pragma unroll
            for (int ni = 0; ni < 2; ++ni) br[pre][ni] = *(const short8*)(bp[ni] + k);
        }
#pragma unroll
        for (int mi = 0; mi < 2; ++mi)
#pragma unroll
            for (int ni = 0; ni < 2; ++ni)
                acc[mi][ni] = __builtin_amdgcn_mfma_f32_16x16x32_bf16(ar[cur][mi], br[cur][ni], acc[mi][ni], 0, 0, 0);
    }

    int nBase = bn * 64 + wn * 32;
    int rowBase = bm * 64 + wm * 32;
#pragma unroll
    for (int mi = 0; mi < 2; ++mi) {
#pragma unroll
        for (int ni = 0; ni < 2; ++ni) {
            int n = nBase + ni * 16 + lr;
            float bv = bias[n];
            int row0 = rowBase + mi * 16 + q * 4;
#pragma unroll
            for (int rr4 = 0; rr4 < 4; ++rr4) {
                int rr = row0 + rr4;
                if (rr < M) {
                    float v = acc[mi][ni][rr4] + bv;
                    if (MODE == 0) {
                        v = fmaxf(v, 0.0f);
                        if (deg[rr] <= 0) v = 0.0f;
                        outB[(long)rr * 1024 + n] = f2bf(v);
                    } else {
                        outF[(long)rr * 256 + n] = v;
                    }
                }
            }
        }
    }
}

extern "C" void kernel_launch(void* const* d_in, const int* in_sizes, int n_in,
                              void* d_out, int out_size, void* d_ws, size_t ws_size,
                              hipStream_t stream) {
    const float* x = (const float*)d_in[0];
    const int* ei = (const int*)d_in[1];
    const float* W[3] = {(const float*)d_in[2], (const float*)d_in[4], (const float*)d_in[6]};
    const float* b[3] = {(const float*)d_in[3], (const float*)d_in[5], (const float*)d_in[7]};
    const float* Wfp = (const float*)d_in[8];
    const float* bfp = (const float*)d_in[9];

    int N = in_sizes[0] / 256;
    int E = in_sizes[1] / 2;
    const int* src = ei;
    const int* dst = ei + E;

    char* p = (char*)d_ws;
    auto alloc = [&](size_t bytes) { char* r = p; p += (bytes + 255) & ~(size_t)255; return r; };
    int* deg = (int*)alloc((size_t)N * 4);
    int* offs = (int*)alloc((size_t)(N + 1) * 4);
    int* cursor = (int*)alloc((size_t)N * 4);
    int* esrc = (int*)alloc((size_t)E * 4);
    unsigned short* Wc[3];
    for (int l = 0; l < 3; l++) Wc[l] = (unsigned short*)alloc(256 * 512 * 2);
    unsigned short* Wft = (unsigned short*)alloc(256 * 1024 * 2);
    unsigned short* Ucat = (unsigned short*)alloc((size_t)N * 1024 * 2);
    unsigned short* Hbar = (unsigned short*)alloc((size_t)N * 256 * 2);

    hipMemsetAsync(deg, 0, (size_t)N * 4, stream);
    int EB = (E + 255) / 256;
    int xblocks = (N * 256 + 2047) / 2048;
    setup_kernel<<<EB + 448 + xblocks, 256, 0, stream>>>(dst, E, deg, W[0], W[1], W[2], Wfp, x,
                                                         Wc[0], Wc[1], Wc[2], Wft, Ucat, N, EB);
    scan_kernel<<<1, 1024, 0, stream>>>(deg, offs, cursor, N);
    fill_kernel<<<EB, 256, 0, stream>>>(src, dst, E, cursor, esrc);

    int gm = (N + 63) / 64;   // 313
    int ab = (N + 3) / 4;     // 5000
    for (int l = 0; l < 3; l++) {
        agg_kernel<<<ab, 256, 0, stream>>>(Ucat + l * 256, offs, esrc, Hbar, N);
        gemm_kernel<0, 512><<<dim3(gm, 4), 256, 0, stream>>>(Ucat + l * 256, Hbar, Wc[l], b[l],
                                                             deg, Ucat + (l + 1) * 256, nullptr, N);
    }
    gemm_kernel<1, 1024><<<dim3(gm, 4), 256, 0, stream>>>(Ucat, nullptr, Wft, bfp, nullptr,
                                                          nullptr, (float*)d_out, N);
}

// Round 6
// 299.635 us; speedup vs baseline: 1.3921x; 1.3921x over previous
//
#include <hip/hip_runtime.h>
#include <hip/hip_bf16.h>

// EdgeGNN: 3x EdgeConv(mean) + final linear.
// Algebra: h'_i = relu( [h_i | mean_j h_j] @ [Wtop - Wbot; Wbot] + b ), 0 if deg==0.
// R6: LDS-staged K-loop (R4 structure, ~5us) + NEW coalesced epilogue: C tile staged in
// LDS, stored as 16B short8/float4 runs (2-4 per thread). R4/R5 timing decomposition
// showed the old scattered 2-byte epilogue stores cost ~40us/GEMM — the real bottleneck.

typedef short short8 __attribute__((ext_vector_type(8)));
typedef float float4v __attribute__((ext_vector_type(4)));

static __device__ __forceinline__ float bf2f(unsigned short u) {
    union { unsigned int i; float f; } c; c.i = ((unsigned int)u) << 16; return c.f;
}
static __device__ __forceinline__ unsigned short f2bf(float f) {
    union { float f; unsigned int i; } c; c.f = f;
    unsigned int u = c.i;
    return (unsigned short)((u + 0x7FFFu + ((u >> 16) & 1u)) >> 16);  // RNE
}

// ---------------- fused setup: deg count + weight prep + x->bf16 ----------------
// blocks [0,EB): count deg.  [EB,EB+192): layer W -> Wc[l] as [n=256][k=512]
//   Wc[n][k] = bf16(W[k][n] - W[k+256][n]) (k<256);  Wc[n][256+k] = bf16(W[k+256][n])
// [EB+192,EB+448): Wf -> Wft [256][1024].  [EB+448,...): x fp32->bf16 into Ucat col 0.
__global__ __launch_bounds__(256)
void setup_kernel(const int* __restrict__ dst, int E, int* __restrict__ deg,
                  const float* __restrict__ W0, const float* __restrict__ W1,
                  const float* __restrict__ W2, const float* __restrict__ Wf,
                  const float* __restrict__ x,
                  unsigned short* __restrict__ Wc0, unsigned short* __restrict__ Wc1,
                  unsigned short* __restrict__ Wc2, unsigned short* __restrict__ Wft,
                  unsigned short* __restrict__ Ucat, int N, int EB) {
    __shared__ float ta[32][33];
    __shared__ float tb[32][33];
    int bb = blockIdx.x;
    int t = threadIdx.x;
    if (bb < EB) {
        int idx = bb * 256 + t;
        if (idx < E) atomicAdd(&deg[dst[idx]], 1);
        return;
    }
    int bb2 = bb - EB;
    int r0 = t >> 5, c = t & 31;
    if (bb2 < 192) {
        const float* W = (bb2 < 64) ? W0 : (bb2 < 128) ? W1 : W2;
        unsigned short* Wc = (bb2 < 64) ? Wc0 : (bb2 < 128) ? Wc1 : Wc2;
        int t64 = bb2 & 63;
        int k0 = (t64 >> 3) * 32, n0 = (t64 & 7) * 32;
#pragma unroll
        for (int it = 0; it < 4; ++it) {
            int r = r0 + it * 8;
            float a = W[(k0 + r) * 256 + n0 + c];
            float bv = W[(k0 + r + 256) * 256 + n0 + c];
            ta[r][c] = a - bv;
            tb[r][c] = bv;
        }
        __syncthreads();
#pragma unroll
        for (int it = 0; it < 4; ++it) {
            int r = r0 + it * 8;  // row in n-space
            Wc[(n0 + r) * 512 + k0 + c] = f2bf(ta[c][r]);
            Wc[(n0 + r) * 512 + 256 + k0 + c] = f2bf(tb[c][r]);
        }
    } else if (bb2 < 448) {
        int t256 = bb2 - 192;
        int k0 = (t256 >> 3) * 32, n0 = (t256 & 7) * 32;
#pragma unroll
        for (int it = 0; it < 4; ++it) {
            int r = r0 + it * 8;
            ta[r][c] = Wf[(k0 + r) * 256 + n0 + c];
        }
        __syncthreads();
#pragma unroll
        for (int it = 0; it < 4; ++it) {
            int r = r0 + it * 8;
            Wft[(n0 + r) * 1024 + k0 + c] = f2bf(ta[c][r]);
        }
    } else {
        long base = (long)(bb2 - 448) * 2048 + t * 8;
        if (base < (long)N * 256) {
            int i = (int)(base >> 8), cc = (int)(base & 255);
            const float4* xp = (const float4*)(x + base);
            float4 v0 = xp[0], v1 = xp[1];
            ushort4 w0, w1;
            w0.x = f2bf(v0.x); w0.y = f2bf(v0.y); w0.z = f2bf(v0.z); w0.w = f2bf(v0.w);
            w1.x = f2bf(v1.x); w1.y = f2bf(v1.y); w1.z = f2bf(v1.z); w1.w = f2bf(v1.w);
            unsigned short* up = Ucat + (long)i * 1024 + cc;
            *(ushort4*)up = w0;
            *(ushort4*)(up + 4) = w1;
        }
    }
}

// ---------------- CSR scan + bucket fill ----------------
__global__ __launch_bounds__(1024) void scan_kernel(const int* __restrict__ deg,
                                                    int* __restrict__ offs,
                                                    int* __restrict__ cursor, int N) {
    __shared__ int sh[1024];
    int t = threadIdx.x;
    int CH = (N + 1023) >> 10;
    int beg = t * CH, end = beg + CH; if (end > N) end = N; if (beg > N) beg = N;
    int s = 0;
    for (int i = beg; i < end; ++i) s += deg[i];
    sh[t] = s;
    __syncthreads();
    for (int off = 1; off < 1024; off <<= 1) {
        int v = 0;
        if (t >= off) v = sh[t - off];
        __syncthreads();
        if (t >= off) sh[t] += v;
        __syncthreads();
    }
    int run = (t > 0) ? sh[t - 1] : 0;
    for (int i = beg; i < end; ++i) {
        offs[i] = run; cursor[i] = run; run += deg[i];
    }
    if (t == 1023) offs[N] = sh[1023];
}

__global__ void fill_kernel(const int* __restrict__ src, const int* __restrict__ dst, int E,
                            int* __restrict__ cursor, int* __restrict__ esrc) {
    int idx = blockIdx.x * 256 + threadIdx.x;
    if (idx < E) {
        int p = atomicAdd(&cursor[dst[idx]], 1);
        esrc[p] = src[idx];
    }
}

// ---------------- gather-mean: Hbar[i] = mean_j H[j] (bf16), one wave per node ----------------
__global__ __launch_bounds__(256)
void agg_kernel(const unsigned short* __restrict__ H, const int* __restrict__ offs,
                const int* __restrict__ esrc, unsigned short* __restrict__ Hbar, int N) {
    int wave = threadIdx.x >> 6, lane = threadIdx.x & 63;
    int i = blockIdx.x * 4 + wave;
    if (i >= N) return;
    int c = lane * 4;
    float a0 = 0.f, a1 = 0.f, a2 = 0.f, a3 = 0.f;
    int e0 = offs[i], e1 = offs[i + 1];
    int e = e0;
    for (; e + 4 <= e1; e += 4) {
        int s0 = esrc[e], s1 = esrc[e + 1], s2 = esrc[e + 2], s3 = esrc[e + 3];
        ushort4 r0 = *(const ushort4*)(H + (long)s0 * 1024 + c);
        ushort4 r1 = *(const ushort4*)(H + (long)s1 * 1024 + c);
        ushort4 r2 = *(const ushort4*)(H + (long)s2 * 1024 + c);
        ushort4 r3 = *(const ushort4*)(H + (long)s3 * 1024 + c);
        a0 += (bf2f(r0.x) + bf2f(r1.x)) + (bf2f(r2.x) + bf2f(r3.x));
        a1 += (bf2f(r0.y) + bf2f(r1.y)) + (bf2f(r2.y) + bf2f(r3.y));
        a2 += (bf2f(r0.z) + bf2f(r1.z)) + (bf2f(r2.z) + bf2f(r3.z));
        a3 += (bf2f(r0.w) + bf2f(r1.w)) + (bf2f(r2.w) + bf2f(r3.w));
    }
    for (; e < e1; ++e) {
        int s0 = esrc[e];
        ushort4 r0 = *(const ushort4*)(H + (long)s0 * 1024 + c);
        a0 += bf2f(r0.x); a1 += bf2f(r0.y); a2 += bf2f(r0.z); a3 += bf2f(r0.w);
    }
    int d = e1 - e0;
    float inv = (d > 0) ? 1.0f / (float)d : 0.0f;
    ushort4 w;
    w.x = f2bf(a0 * inv); w.y = f2bf(a1 * inv); w.z = f2bf(a2 * inv); w.w = f2bf(a3 * inv);
    *(ushort4*)(Hbar + (long)i * 256 + c) = w;
}

// ---------------- bf16 MFMA GEMM, 64x64 tile, LDS-staged K-loop + coalesced epilogue ----------
// A (MODE 0): k<256 from A1 (stride 1024, Ucat window), k>=256 from A2 (stride 256, Hbar).
// A (MODE 1): A1 stride 1024, K=1024.  Bt: [n=256][K] (Wc/Wft).
// Epilogue: stage C in LDS (reusing staging buffer), store 16B-coalesced.
#define LDK 72

template <int MODE, int K>
__global__ __launch_bounds__(256)
void gemm_kernel(const unsigned short* __restrict__ A1,
                 const unsigned short* __restrict__ A2,
                 const unsigned short* __restrict__ Bt,
                 const float* __restrict__ bias,
                 const int* __restrict__ deg,
                 unsigned short* __restrict__ outB,
                 float* __restrict__ outF,
                 int M) {
    __shared__ __align__(16) unsigned char smem[64 * LDK * 2 * 2];  // 18432 B
    unsigned short* ldsA = (unsigned short*)smem;
    unsigned short* ldsB = ldsA + 64 * LDK;
    constexpr int NIT = K / 64;
    int t = threadIdx.x;
    int bm = blockIdx.x, bn = blockIdx.y;
    int lane = t & 63, wave = t >> 6;
    int wm = wave >> 1, wn = wave & 1;
    int lr = lane & 15, q = lane >> 4;

    float4v acc[2][2];
#pragma unroll
    for (int i = 0; i < 2; i++)
#pragma unroll
        for (int j = 0; j < 2; j++) { float4v z = {0.f, 0.f, 0.f, 0.f}; acc[i][j] = z; }

    int r = t >> 2;        // staging row 0..63
    int quarter = t & 3;   // 16-elem chunk within the 64-elem k-slice
    int rowA = bm * 64 + r;
    if (rowA >= M) rowA = M - 1;  // clamp: duplicate row, stores masked below
    const unsigned short* gB0 = Bt + (long)(bn * 64 + r) * K + quarter * 16;
    unsigned short* sA = ldsA + r * LDK + quarter * 16;
    unsigned short* sB = ldsB + r * LDK + quarter * 16;

    auto addrA = [&](int kk) -> const unsigned short* {
        if (MODE == 1 || kk < 256) return A1 + (long)rowA * 1024 + kk + quarter * 16;
        return A2 + (long)rowA * 256 + (kk - 256) + quarter * 16;
    };

    // prologue
    const unsigned short* pa = addrA(0);
    uint4 a0 = *(const uint4*)pa;
    uint4 a1 = *(const uint4*)(pa + 8);
    uint4 b0 = *(const uint4*)gB0;
    uint4 b1 = *(const uint4*)(gB0 + 8);

    for (int it = 0; it < NIT; ++it) {
        __syncthreads();
        *(uint4*)sA = a0; *(uint4*)(sA + 8) = a1;
        *(uint4*)sB = b0; *(uint4*)(sB + 8) = b1;
        __syncthreads();
        if (it + 1 < NIT) {
            int kn = (it + 1) << 6;
            const unsigned short* pn = addrA(kn);
            a0 = *(const uint4*)pn;
            a1 = *(const uint4*)(pn + 8);
            b0 = *(const uint4*)(gB0 + kn);
            b1 = *(const uint4*)(gB0 + kn + 8);
        }
#pragma unroll
        for (int ks = 0; ks < 2; ++ks) {
            short8 af[2], bfr[2];
#pragma unroll
            for (int mi = 0; mi < 2; ++mi)
                af[mi] = *(const short8*)(ldsA + (wm * 32 + mi * 16 + lr) * LDK + ks * 32 + q * 8);
#pragma unroll
            for (int ni = 0; ni < 2; ++ni)
                bfr[ni] = *(const short8*)(ldsB + (wn * 32 + ni * 16 + lr) * LDK + ks * 32 + q * 8);
#pragma unroll
            for (int mi = 0; mi < 2; ++mi)
#pragma unroll
                for (int ni = 0; ni < 2; ++ni)
                    acc[mi][ni] = __builtin_amdgcn_mfma_f32_16x16x32_bf16(af[mi], bfr[ni], acc[mi][ni], 0, 0, 0);
        }
    }

    __syncthreads();  // all waves done reading ldsA/ldsB; reuse smem for C tile

    if (MODE == 0) {
        // stage bf16 C tile [64][LDK] then coalesced 16B stores (2 per thread)
        unsigned short* C = (unsigned short*)smem;
#pragma unroll
        for (int mi = 0; mi < 2; ++mi) {
#pragma unroll
            for (int ni = 0; ni < 2; ++ni) {
                int cn = wn * 32 + ni * 16 + lr;
                float bv = bias[bn * 64 + cn];
                int rl0 = wm * 32 + mi * 16 + q * 4;
#pragma unroll
                for (int r4 = 0; r4 < 4; ++r4) {
                    float v = fmaxf(acc[mi][ni][r4] + bv, 0.0f);
                    C[(rl0 + r4) * LDK + cn] = f2bf(v);
                }
            }
        }
        __syncthreads();
#pragma unroll
        for (int j = 0; j < 2; ++j) {
            int chunk = t + j * 256;       // 512 chunks: 64 rows x 8 x 16B
            int row = chunk >> 3, h = chunk & 7;
            int rg = bm * 64 + row;
            if (rg < M) {
                short8 v = *(const short8*)(C + row * LDK + h * 8);
                if (deg[rg] <= 0) { short8 z = {0, 0, 0, 0, 0, 0, 0, 0}; v = z; }
                *(short8*)(outB + (long)rg * 1024 + bn * 64 + h * 8) = v;
            }
        }
    } else {
        // stage fp32 C tile [64][68] (17408 B) then coalesced float4 stores (4 per thread)
        float* Cf = (float*)smem;
#pragma unroll
        for (int mi = 0; mi < 2; ++mi) {
#pragma unroll
            for (int ni = 0; ni < 2; ++ni) {
                int cn = wn * 32 + ni * 16 + lr;
                float bv = bias[bn * 64 + cn];
                int rl0 = wm * 32 + mi * 16 + q * 4;
#pragma unroll
                for (int r4 = 0; r4 < 4; ++r4)
                    Cf[(rl0 + r4) * 68 + cn] = acc[mi][ni][r4] + bv;
            }
        }
        __syncthreads();
#pragma unroll
        for (int j = 0; j < 4; ++j) {
            int chunk = t + j * 256;       // 1024 chunks: 64 rows x 16 x 16B
            int row = chunk >> 4, h = chunk & 15;
            int rg = bm * 64 + row;
            if (rg < M) {
                float4 v = *(const float4*)(Cf + row * 68 + h * 4);
                *(float4*)(outF + (long)rg * 256 + bn * 64 + h * 4) = v;
            }
        }
    }
}

extern "C" void kernel_launch(void* const* d_in, const int* in_sizes, int n_in,
                              void* d_out, int out_size, void* d_ws, size_t ws_size,
                              hipStream_t stream) {
    const float* x = (const float*)d_in[0];
    const int* ei = (const int*)d_in[1];
    const float* W[3] = {(const float*)d_in[2], (const float*)d_in[4], (const float*)d_in[6]};
    const float* b[3] = {(const float*)d_in[3], (const float*)d_in[5], (const float*)d_in[7]};
    const float* Wfp = (const float*)d_in[8];
    const float* bfp = (const float*)d_in[9];

    int N = in_sizes[0] / 256;
    int E = in_sizes[1] / 2;
    const int* src = ei;
    const int* dst = ei + E;

    char* p = (char*)d_ws;
    auto alloc = [&](size_t bytes) { char* r = p; p += (bytes + 255) & ~(size_t)255; return r; };
    int* deg = (int*)alloc((size_t)N * 4);
    int* offs = (int*)alloc((size_t)(N + 1) * 4);
    int* cursor = (int*)alloc((size_t)N * 4);
    int* esrc = (int*)alloc((size_t)E * 4);
    unsigned short* Wc[3];
    for (int l = 0; l < 3; l++) Wc[l] = (unsigned short*)alloc(256 * 512 * 2);
    unsigned short* Wft = (unsigned short*)alloc(256 * 1024 * 2);
    unsigned short* Ucat = (unsigned short*)alloc((size_t)N * 1024 * 2);
    unsigned short* Hbar = (unsigned short*)alloc((size_t)N * 256 * 2);

    hipMemsetAsync(deg, 0, (size_t)N * 4, stream);
    int EB = (E + 255) / 256;
    int xblocks = (N * 256 + 2047) / 2048;
    setup_kernel<<<EB + 448 + xblocks, 256, 0, stream>>>(dst, E, deg, W[0], W[1], W[2], Wfp, x,
                                                         Wc[0], Wc[1], Wc[2], Wft, Ucat, N, EB);
    scan_kernel<<<1, 1024, 0, stream>>>(deg, offs, cursor, N);
    fill_kernel<<<EB, 256, 0, stream>>>(src, dst, E, cursor, esrc);

    int gm = (N + 63) / 64;   // 313
    int ab = (N + 3) / 4;     // 5000
    for (int l = 0; l < 3; l++) {
        agg_kernel<<<ab, 256, 0, stream>>>(Ucat + l * 256, offs, esrc, Hbar, N);
        gemm_kernel<0, 512><<<dim3(gm, 4), 256, 0, stream>>>(Ucat + l * 256, Hbar, Wc[l], b[l],
                                                             deg, Ucat + (l + 1) * 256, nullptr, N);
    }
    gemm_kernel<1, 1024><<<dim3(gm, 4), 256, 0, stream>>>(Ucat, nullptr, Wft, bfp, nullptr,
                                                          nullptr, (float*)d_out, N);
}